// Round 1
// baseline (274.388 us; speedup 1.0000x reference)
//
#include <hip/hip_runtime.h>
#include <utility>
#include <type_traits>

// ================= compile-time math (mirrors reference) =================
constexpr int cabs_i(int x){ return x < 0 ? -x : x; }
constexpr int cmax_i(int a, int b){ return a > b ? a : b; }
constexpr int cmin_i(int a, int b){ return a < b ? a : b; }
constexpr double cfact(int n){ double r = 1.0; for (int i = 2; i <= n; ++i) r *= (double)i; return r; }
constexpr double csqrt_d(double x){
  if (x <= 0.0) return 0.0;
  double r = x > 1.0 ? x : 1.0;
  for (int i = 0; i < 64; ++i) r = 0.5 * (r + x / r);
  return r;
}
constexpr double cg_coef(int j1,int j2,int m1,int m2,int j,int m){
  if (m1 + m2 != m || j < cabs_i(j1 - j2) || j > j1 + j2) return 0.0;
  if (cabs_i(m1) > j1 || cabs_i(m2) > j2 || cabs_i(m) > j) return 0.0;
  double pref = csqrt_d((2.0*j + 1.0) * cfact(j1+j2-j) * cfact(j+j1-j2) * cfact(j+j2-j1) / cfact(j1+j2+j+1));
  pref *= csqrt_d(cfact(j+m)*cfact(j-m)*cfact(j1-m1)*cfact(j1+m1)*cfact(j2-m2)*cfact(j2+m2));
  double s = 0.0;
  const int k0 = cmax_i(0, cmax_i(j2-j-m1, j1+m2-j));
  const int k1 = cmin_i(j1+j2-j, cmin_i(j1-m1, j2+m2));
  for (int k = k0; k <= k1; ++k){
    double t = 1.0/(cfact(k)*cfact(j1+j2-j-k)*cfact(j1-m1-k)*cfact(j2+m2-k)*cfact(j-j2+m1+k)*cfact(j-j1-m2+k));
    s += (k & 1) ? -t : t;
  }
  return pref * s;
}
constexpr double wd_coef(int j,int m1,int m2,int s){
  double pref = csqrt_d(cfact(j+m1)*cfact(j-m1)*cfact(j+m2)*cfact(j-m2));
  double c = pref / (cfact(j+m2-s)*cfact(s)*cfact(m1-m2+s)*cfact(j-m1-s));
  return ((m1-m2+s) & 1) ? -c : c;
}
constexpr double cgetp(double M0,double M1,double M2){
  double s = M1+M2, d = M1-M2;
  double p = (M0-s)*(M0+s)*(M0-d)*(M0+d);
  double pp = 0.5*(p + (p < 0 ? -p : p));
  return csqrt_d(pp)/(2.0*M0);
}

// ================= static_for =================
template<int Start, class F, int... Is>
__device__ inline void static_for_impl(F&& f, std::integer_sequence<int, Is...>){
  (f(std::integral_constant<int, Start + Is>{}), ...);
}
template<int Start, int End, class F>   // [Start, End)
__device__ inline void static_for(F&& f){
  if constexpr (End > Start)
    static_for_impl<Start>(static_cast<F&&>(f), std::make_integer_sequence<int, End - Start>{});
}

// ================= complex =================
struct cplx { float re, im; };
__device__ inline cplx operator+(cplx a, cplx b){ return {a.re + b.re, a.im + b.im}; }
__device__ inline cplx operator*(cplx a, cplx b){ return {a.re*b.re - a.im*b.im, a.re*b.im + a.im*b.re}; }
__device__ inline cplx cscale(cplx a, float s){ return {a.re*s, a.im*s}; }
__device__ inline cplx cconj(cplx a){ return {a.re, -a.im}; }
template<int n> __device__ inline cplx cpow(cplx e){
  if constexpr (n == 0) return cplx{1.f, 0.f};
  else if constexpr (n == 1) return e;
  else if constexpr (n == -1) return cconj(e);
  else if constexpr (n == 2) return e * e;
  else /* n == -2 */ return cconj(e * e);
}
template<int n> __device__ inline float ipow(float x){
  if constexpr (n <= 0) return 1.f;
  else return x * ipow<n-1>(x);
}

// ================= wigner d (coeffs folded at compile time) =================
template<int j, int m1, int m2>
__device__ inline float wigner_d(float ch, float sh){
  constexpr int s0 = cmax_i(0, m2 - m1);
  constexpr int s1 = cmin_i(j - m1, j + m2);
  float out = 0.f;
  static_for<s0, s1 + 1>([&](auto S){
    constexpr int s = decltype(S)::value;
    constexpr float coef = (float)wd_coef(j, m1, m2, s);
    out += coef * ipow<2*j + m2 - m1 - 2*s>(ch) * ipow<m1 - m2 + 2*s>(sh);
  });
  return out;
}

// ================= static LS layout (from reference _build_layout) =================
struct LS { int l, s; };
template<int E> struct Entry;
// Res0 Zc_4025 (BD, J=1): e0 off 0, e1 off 2
template<> struct Entry<0>{ static constexpr int off = 0;  static constexpr int n = 2; static constexpr LS ls[2] = {{0,1},{2,1}}; };
template<> struct Entry<1>{ static constexpr int off = 2;  static constexpr int n = 3; static constexpr LS ls[3] = {{0,1},{2,1},{2,2}}; };
// Res1 D2_2460 (BC, J=2): e0 off 5, e1 off 10
template<> struct Entry<2>{ static constexpr int off = 5;  static constexpr int n = 5; static constexpr LS ls[5] = {{0,1},{2,1},{2,2},{2,3},{4,3}}; };
template<> struct Entry<3>{ static constexpr int off = 10; static constexpr int n = 1; static constexpr LS ls[1] = {{2,1}}; };
// Res2 D1_2420 (CD, J=1): e0 off 11, e1 off 14
template<> struct Entry<4>{ static constexpr int off = 11; static constexpr int n = 3; static constexpr LS ls[3] = {{0,1},{2,1},{2,2}}; };
template<> struct Entry<5>{ static constexpr int off = 14; static constexpr int n = 2; static constexpr LS ls[2] = {{0,1},{2,1}}; };

template<int E,int ja,int jb,int jc,int lb,int lc>
constexpr double hcoef(int idx){
  return cg_coef(jb, jc, lb, -lc, Entry<E>::ls[idx].s, lb - lc)
       * cg_coef(Entry<E>::ls[idx].l, Entry<E>::ls[idx].s, 0, lb - lc, ja, lb - lc);
}
template<int E,int ja,int jb,int jc,int lb,int lc>
constexpr bool hnz(){
  bool any = false;
  for (int i = 0; i < Entry<E>::n; ++i) if (hcoef<E,ja,jb,jc,lb,lc>(i) != 0.0) any = true;
  return any;
}
template<int E,int ja,int jb,int jc,int lb,int lc>
__device__ inline cplx H_ls(const cplx* par){
  cplx tot{0.f, 0.f};
  static_for<0, Entry<E>::n>([&](auto I){
    constexpr double c = hcoef<E,ja,jb,jc,lb,lc>(decltype(I)::value);
    if constexpr (c != 0.0){
      cplx p = par[Entry<E>::off + decltype(I)::value];
      tot.re += (float)c * p.re;
      tot.im += (float)c * p.im;
    }
  });
  return tot;
}

// ================= physics constants =================
constexpr double dM0B = 2.01026, dM0C = 0.13957061, dM0D = 2.00685;
constexpr float  M0B = (float)dM0B, M0C = (float)dM0C, M0D = (float)dM0D;
constexpr float R0_m0 = 4.026f,  R0_g0 = 0.025f;   // BD chain, J=1
constexpr float R1_m0 = 2.4607f, R1_g0 = 0.0475f;  // BC chain, J=2
constexpr float R2_m0 = 2.4232f, R2_g0 = 0.025f;   // CD chain, J=1
constexpr float Q0_0 = (float)cgetp(4.026,  dM0B, dM0D);
constexpr float Q0_1 = (float)cgetp(2.4607, dM0B, dM0C);
constexpr float Q0_2 = (float)cgetp(2.4232, dM0C, dM0D);

__device__ inline float getp(float M0, float M1, float M2){
  float s = M1 + M2, d = M1 - M2;
  float p = (M0 - s) * (M0 + s) * (M0 - d) * (M0 + d);
  float pp = 0.5f * (p + fabsf(p));
  return sqrtf(pp) / (2.f * M0);
}
__device__ inline cplx bw_eval(float m, float m0, float g0, float q, float q0){
  float gamma = g0 * (q / q0) * (m0 / m);
  float num   = m0 * gamma;                 // real numerator
  float den_re = (m0 + m) * (m0 - m);
  float den_im = -m0 * gamma;
  float inv = 1.f / (den_re * den_re + den_im * den_im);
  return { num * den_re * inv, -num * den_im * inv };
}

// ================= kernel =================
__global__ void __launch_bounds__(256)
AllAmplitude_59665685676511_kernel(
    const float* __restrict__ g_mBC,  const float* __restrict__ g_mBD,  const float* __restrict__ g_mCD,
    const float* __restrict__ g_cBC,  const float* __restrict__ g_cBBC, const float* __restrict__ g_pBC,  const float* __restrict__ g_pBBC,
    const float* __restrict__ g_cBD,  const float* __restrict__ g_cDBD, const float* __restrict__ g_pDBD,
    const float* __restrict__ g_cCD,  const float* __restrict__ g_cCCD, const float* __restrict__ g_pCD,  const float* __restrict__ g_pCCD,
    const float* __restrict__ g_cT1,  const float* __restrict__ g_cT2,  const float* __restrict__ g_p1,   const float* __restrict__ g_p2,
    const float2* __restrict__ g_par, float* __restrict__ out, int n)
{
  int i = blockIdx.x * blockDim.x + threadIdx.x;
  if (i >= n) return;

  // params -> registers (uniform, L1-broadcast)
  cplx par[16];
  #pragma unroll
  for (int k = 0; k < 16; ++k) { float2 p = g_par[k]; par[k] = {p.x, p.y}; }

  const float mBC = g_mBC[i], mBD = g_mBD[i], mCD = g_mCD[i];

  // Breit-Wigners (order = resonance table order)
  const cplx bw0 = bw_eval(mBD, R0_m0, R0_g0, getp(mBD, M0B, M0D), Q0_0);
  const cplx bw1 = bw_eval(mBC, R1_m0, R1_g0, getp(mBC, M0B, M0C), Q0_1);
  const cplx bw2 = bw_eval(mCD, R2_m0, R2_g0, getp(mCD, M0C, M0D), Q0_2);

  // half-angle ch/sh per angle
  float c, chBD, shBD, chDBD, shDBD, chBC, shBC, chBBC, shBBC, chCD, shCD, chCCD, shCCD, chT1, shT1, chT2, shT2;
  c = g_cBD[i];  chBD  = sqrtf((1.f + c) * 0.5f); shBD  = sqrtf((1.f - c) * 0.5f);
  c = g_cDBD[i]; chDBD = sqrtf((1.f + c) * 0.5f); shDBD = sqrtf((1.f - c) * 0.5f);
  c = g_cBC[i];  chBC  = sqrtf((1.f + c) * 0.5f); shBC  = sqrtf((1.f - c) * 0.5f);
  c = g_cBBC[i]; chBBC = sqrtf((1.f + c) * 0.5f); shBBC = sqrtf((1.f - c) * 0.5f);
  c = g_cCD[i];  chCD  = sqrtf((1.f + c) * 0.5f); shCD  = sqrtf((1.f - c) * 0.5f);
  c = g_cCCD[i]; chCCD = sqrtf((1.f + c) * 0.5f); shCCD = sqrtf((1.f - c) * 0.5f);
  c = g_cT1[i];  chT1  = sqrtf((1.f + c) * 0.5f); shT1  = sqrtf((1.f - c) * 0.5f);
  c = g_cT2[i];  chT2  = sqrtf((1.f + c) * 0.5f); shT2  = sqrtf((1.f - c) * 0.5f);

  // phase bases: e_X = exp(-i * phi_X); combined where exponents always co-occur
  float sv, cv;
  __builtin_sincosf(g_pDBD[i],            &sv, &cv); const cplx eD  {cv, -sv};
  __builtin_sincosf(g_pBC[i],             &sv, &cv); const cplx eBC {cv, -sv};
  __builtin_sincosf(g_p1[i] + g_pBBC[i],  &sv, &cv); const cplx eP1 {cv, -sv};
  __builtin_sincosf(g_pCD[i],             &sv, &cv); const cplx eCD {cv, -sv};
  __builtin_sincosf(g_p2[i] + g_pCCD[i],  &sv, &cv); const cplx eP2 {cv, -sv};

  float total = 0.f;
  static_for<0, 2>([&](auto IA){ constexpr int lA = (decltype(IA)::value == 0) ? -1 : 1;
    static_for<-1, 2>([&](auto IB){ constexpr int lB = decltype(IB)::value;
      constexpr int lC = 0;
      static_for<-1, 2>([&](auto ID){ constexpr int lD = decltype(ID)::value;
        cplx amp{0.f, 0.f};

        // ---- res 0: Zc_4025, BD chain, J=1 ----
        {
          cplx ar{0.f, 0.f};
          static_for<-1, 2>([&](auto IDB){ constexpr int lDB = decltype(IDB)::value;
            constexpr int mDB = lD - lB;
            if constexpr (cabs_i(mDB) <= 1) {
              constexpr bool f1 = hnz<0, 1,1,0, lDB, lC>();
              constexpr bool f2 = hnz<1, 1,1,1, lD,  lB>();
              if constexpr (f1 && f2) {
                cplx H1 = H_ls<0, 1,1,0, lDB, lC>(par);
                cplx H2 = H_ls<1, 1,1,1, lD,  lB>(par);
                float d1 = wigner_d<1, lA, lDB - lC>(chBD, shBD);
                float d2 = wigner_d<1, lDB, mDB>(chDBD, shDBD);
                ar = ar + (H1 * H2) * cscale(cpow<lD>(eD), d1 * d2);
              }
            }
          });
          amp = amp + ar * bw0;
        }

        // ---- res 1: D2_2460, BC chain, J=2 ----
        {
          cplx ar{0.f, 0.f};
          static_for<-2, 3>([&](auto IBC){ constexpr int lBC = decltype(IBC)::value;
            static_for<-1, 2>([&](auto IB2){ constexpr int lB2 = decltype(IB2)::value;
              constexpr int mBC1 = lBC - lD;
              if constexpr (cabs_i(mBC1) <= 1) {
                constexpr bool f1 = hnz<2, 1,2,1, lBC, lD>();
                constexpr bool f2 = hnz<3, 2,1,0, lB2, lC>();
                if constexpr (f1 && f2) {
                  cplx H1 = H_ls<2, 1,2,1, lBC, lD>(par);
                  cplx H2 = H_ls<3, 2,1,0, lB2, lC>(par);
                  float da = wigner_d<1, lB2, lB>(chT1, shT1);
                  float d1 = wigner_d<1, lA, mBC1>(chBC, shBC);
                  float d2 = wigner_d<2, lBC, lB2 - lC>(chBBC, shBBC);
                  cplx ph = cpow<lB2>(eP1) * cpow<lBC>(eBC);
                  ar = ar + (H1 * H2) * cscale(ph, da * d1 * d2);
                }
              }
            });
          });
          amp = amp + ar * bw1;
        }

        // ---- res 2: D1_2420, CD chain, J=1 ----
        {
          cplx ar{0.f, 0.f};
          static_for<-1, 2>([&](auto ICD){ constexpr int lCD = decltype(ICD)::value;
            static_for<-1, 2>([&](auto IC2){ constexpr int lC2 = decltype(IC2)::value;
              constexpr int mCD1 = lCD - lB;
              if constexpr (cabs_i(mCD1) <= 1) {
                constexpr bool f1 = hnz<4, 1,1,1, lCD, lB>();
                constexpr bool f2 = hnz<5, 1,0,1, lC,  lC2>();
                if constexpr (f1 && f2) {
                  cplx H1 = H_ls<4, 1,1,1, lCD, lB>(par);
                  cplx H2 = H_ls<5, 1,0,1, lC,  lC2>(par);
                  float da = wigner_d<1, lC2, lD>(chT2, shT2);
                  float d1 = wigner_d<1, lA, mCD1>(chCD, shCD);
                  float d2 = wigner_d<1, lCD, lC2 - lC>(chCCD, shCCD);
                  cplx ph = cpow<lC2>(eP2) * cpow<lCD>(eCD);
                  ar = ar + (H1 * H2) * cscale(ph, da * d1 * d2);
                }
              }
            });
          });
          amp = amp + ar * bw2;
        }

        total += amp.re * amp.re + amp.im * amp.im;
      });
    });
  });

  out[i] = total;
}

// ================= launch =================
extern "C" void kernel_launch(void* const* d_in, const int* in_sizes, int n_in,
                              void* d_out, int out_size, void* d_ws, size_t ws_size,
                              hipStream_t stream) {
  (void)n_in; (void)d_ws; (void)ws_size; (void)out_size;
  const int n = in_sizes[0];
  const float*  mBC  = (const float*)d_in[0];
  const float*  mBD  = (const float*)d_in[1];
  const float*  mCD  = (const float*)d_in[2];
  const float*  cBC  = (const float*)d_in[3];
  const float*  cBBC = (const float*)d_in[4];
  const float*  pBC  = (const float*)d_in[5];
  const float*  pBBC = (const float*)d_in[6];
  const float*  cBD  = (const float*)d_in[7];
  const float*  cDBD = (const float*)d_in[8];
  const float*  pDBD = (const float*)d_in[9];
  const float*  cCD  = (const float*)d_in[10];
  const float*  cCCD = (const float*)d_in[11];
  const float*  pCD  = (const float*)d_in[12];
  const float*  pCCD = (const float*)d_in[13];
  const float*  cT1  = (const float*)d_in[14];
  const float*  cT2  = (const float*)d_in[15];
  const float*  p1   = (const float*)d_in[16];
  const float*  p2   = (const float*)d_in[17];
  const float2* parm = (const float2*)d_in[18];

  dim3 block(256);
  dim3 grid((n + 255) / 256);
  AllAmplitude_59665685676511_kernel<<<grid, block, 0, stream>>>(
      mBC, mBD, mCD, cBC, cBBC, pBC, pBBC, cBD, cDBD, pDBD,
      cCD, cCCD, pCD, pCCD, cT1, cT2, p1, p2, parm, (float*)d_out, n);
}

// Round 2
// 65.500 us; speedup vs baseline: 4.1891x; 4.1891x over previous
//
#include <hip/hip_runtime.h>
#include <utility>
#include <type_traits>

// ================= compile-time math (mirrors reference) =================
constexpr int cabs_i(int x){ return x < 0 ? -x : x; }
constexpr int cmax_i(int a, int b){ return a > b ? a : b; }
constexpr int cmin_i(int a, int b){ return a < b ? a : b; }
constexpr double cfact(int n){ double r = 1.0; for (int i = 2; i <= n; ++i) r *= (double)i; return r; }
constexpr double csqrt_d(double x){
  if (x <= 0.0) return 0.0;
  double r = x > 1.0 ? x : 1.0;
  for (int i = 0; i < 64; ++i) r = 0.5 * (r + x / r);
  return r;
}
constexpr double cg_coef(int j1,int j2,int m1,int m2,int j,int m){
  if (m1 + m2 != m || j < cabs_i(j1 - j2) || j > j1 + j2) return 0.0;
  if (cabs_i(m1) > j1 || cabs_i(m2) > j2 || cabs_i(m) > j) return 0.0;
  double pref = csqrt_d((2.0*j + 1.0) * cfact(j1+j2-j) * cfact(j+j1-j2) * cfact(j+j2-j1) / cfact(j1+j2+j+1));
  pref *= csqrt_d(cfact(j+m)*cfact(j-m)*cfact(j1-m1)*cfact(j1+m1)*cfact(j2-m2)*cfact(j2+m2));
  double s = 0.0;
  const int k0 = cmax_i(0, cmax_i(j2-j-m1, j1+m2-j));
  const int k1 = cmin_i(j1+j2-j, cmin_i(j1-m1, j2+m2));
  for (int k = k0; k <= k1; ++k){
    double t = 1.0/(cfact(k)*cfact(j1+j2-j-k)*cfact(j1-m1-k)*cfact(j2+m2-k)*cfact(j-j2+m1+k)*cfact(j-j1-m2+k));
    s += (k & 1) ? -t : t;
  }
  return pref * s;
}
constexpr double wd_coef(int j,int m1,int m2,int s){
  double pref = csqrt_d(cfact(j+m1)*cfact(j-m1)*cfact(j+m2)*cfact(j-m2));
  double c = pref / (cfact(j+m2-s)*cfact(s)*cfact(m1-m2+s)*cfact(j-m1-s));
  return ((m1-m2+s) & 1) ? -c : c;
}
constexpr double cgetp(double M0,double M1,double M2){
  double s = M1+M2, d = M1-M2;
  double p = (M0-s)*(M0+s)*(M0-d)*(M0+d);
  double pp = 0.5*(p + (p < 0 ? -p : p));
  return csqrt_d(pp)/(2.0*M0);
}

// ================= static_for =================
template<int Start, class F, int... Is>
__device__ inline void static_for_impl(F&& f, std::integer_sequence<int, Is...>){
  (f(std::integral_constant<int, Start + Is>{}), ...);
}
template<int Start, int End, class F>   // [Start, End)
__device__ inline void static_for(F&& f){
  if constexpr (End > Start)
    static_for_impl<Start>(static_cast<F&&>(f), std::make_integer_sequence<int, End - Start>{});
}

// ================= complex =================
struct cplx { float re, im; };
__device__ inline cplx operator+(cplx a, cplx b){ return {a.re + b.re, a.im + b.im}; }
__device__ inline cplx operator*(cplx a, cplx b){
  return { fmaf(a.re, b.re, -(a.im*b.im)), fmaf(a.re, b.im, a.im*b.re) };
}
__device__ inline cplx cconj(cplx a){ return {a.re, -a.im}; }
__device__ inline void caxpy(cplx& acc, float r, cplx x){
  acc.re = fmaf(r, x.re, acc.re); acc.im = fmaf(r, x.im, acc.im);
}
template<int n> __device__ inline float ipow(float x){
  if constexpr (n <= 0) return 1.f;
  else return x * ipow<n-1>(x);
}

// ================= wigner d (coeffs folded at compile time) =================
template<int j, int m1, int m2>
__device__ inline float wigner_d(float ch, float sh){
  constexpr int s0 = cmax_i(0, m2 - m1);
  constexpr int s1 = cmin_i(j - m1, j + m2);
  float out = 0.f;
  static_for<s0, s1 + 1>([&](auto S){
    constexpr int s = decltype(S)::value;
    constexpr float coef = (float)wd_coef(j, m1, m2, s);
    out = fmaf(coef, ipow<2*j + m2 - m1 - 2*s>(ch) * ipow<m1 - m2 + 2*s>(sh), out);
  });
  return out;
}

// ================= static LS layout (from reference _build_layout) =================
struct LS { int l, s; };
template<int E> struct Entry;
template<> struct Entry<0>{ static constexpr int off = 0;  static constexpr int n = 2; static constexpr LS ls[2] = {{0,1},{2,1}}; };
template<> struct Entry<1>{ static constexpr int off = 2;  static constexpr int n = 3; static constexpr LS ls[3] = {{0,1},{2,1},{2,2}}; };
template<> struct Entry<2>{ static constexpr int off = 5;  static constexpr int n = 5; static constexpr LS ls[5] = {{0,1},{2,1},{2,2},{2,3},{4,3}}; };
template<> struct Entry<3>{ static constexpr int off = 10; static constexpr int n = 1; static constexpr LS ls[1] = {{2,1}}; };
template<> struct Entry<4>{ static constexpr int off = 11; static constexpr int n = 3; static constexpr LS ls[3] = {{0,1},{2,1},{2,2}}; };
template<> struct Entry<5>{ static constexpr int off = 14; static constexpr int n = 2; static constexpr LS ls[2] = {{0,1},{2,1}}; };

template<int E,int ja,int jb,int jc,int lb,int lc>
constexpr double hcoef(int idx){
  return cg_coef(jb, jc, lb, -lc, Entry<E>::ls[idx].s, lb - lc)
       * cg_coef(Entry<E>::ls[idx].l, Entry<E>::ls[idx].s, 0, lb - lc, ja, lb - lc);
}
template<int E,int ja,int jb,int jc,int lb,int lc>
constexpr bool hnz(){
  bool any = false;
  for (int i = 0; i < Entry<E>::n; ++i) if (hcoef<E,ja,jb,jc,lb,lc>(i) != 0.0) any = true;
  return any;
}
template<int E,int ja,int jb,int jc,int lb,int lc>
__device__ inline cplx H_ls(const cplx* par){
  cplx tot{0.f, 0.f};
  static_for<0, Entry<E>::n>([&](auto I){
    constexpr double c = hcoef<E,ja,jb,jc,lb,lc>(decltype(I)::value);
    if constexpr (c != 0.0){
      cplx p = par[Entry<E>::off + decltype(I)::value];
      tot.re = fmaf((float)c, p.re, tot.re);
      tot.im = fmaf((float)c, p.im, tot.im);
    }
  });
  return tot;
}

// ================= H table layout in d_ws =================
constexpr int IH10(int lDB){ return lDB+1; }                       // 0..2
constexpr int IH20(int lD,int lB){ return 3+(lD+1)*3+(lB+1); }     // 3..11
constexpr int IH11(int lBC,int lD){ return 12+(lBC+2)*3+(lD+1); }  // 12..26
constexpr int IH21(int lB2){ return 27+(lB2+1)/2; }                // 27..28
constexpr int IH12(int lCD,int lB){ return 29+(lCD+1)*3+(lB+1); }  // 29..37
constexpr int IH22(int lC2){ return 38+(lC2+1); }                  // 38..40
constexpr int NH = 41;

__device__ inline void compute_htab(const float2* __restrict__ g_par, cplx* t){
  cplx par[16];
  #pragma unroll
  for (int k = 0; k < 16; ++k){ float2 p = g_par[k]; par[k] = {p.x, p.y}; }
  static_for<-1,2>([&](auto L){ constexpr int l = decltype(L)::value; t[IH10(l)] = H_ls<0,1,1,0,l,0>(par); });
  static_for<-1,2>([&](auto D){ constexpr int lD = decltype(D)::value;
    static_for<-1,2>([&](auto B){ constexpr int lB = decltype(B)::value;
      t[IH20(lD,lB)] = H_ls<1,1,1,1,lD,lB>(par); }); });
  static_for<-2,3>([&](auto C){ constexpr int lBC = decltype(C)::value;
    static_for<-1,2>([&](auto D){ constexpr int lD = decltype(D)::value;
      t[IH11(lBC,lD)] = H_ls<2,1,2,1,lBC,lD>(par); }); });
  t[IH21(-1)] = H_ls<3,2,1,0,-1,0>(par);
  t[IH21( 1)] = H_ls<3,2,1,0, 1,0>(par);
  static_for<-1,2>([&](auto C){ constexpr int lCD = decltype(C)::value;
    static_for<-1,2>([&](auto B){ constexpr int lB = decltype(B)::value;
      t[IH12(lCD,lB)] = H_ls<4,1,1,1,lCD,lB>(par); }); });
  static_for<-1,2>([&](auto C){ constexpr int lC2 = decltype(C)::value;
    t[IH22(lC2)] = H_ls<5,1,0,1,0,lC2>(par); });
}

template<int IDX, bool PRE>
__device__ inline cplx getH(const float2* __restrict__ hs, const cplx* ht){
  if constexpr (PRE){ float2 v = hs[IDX]; return cplx{v.x, v.y}; }
  else return ht[IDX];
}
#define GH(IDX) getH<(IDX), PRE>(hs, ht)

// ================= physics constants =================
constexpr double dM0B = 2.01026, dM0C = 0.13957061, dM0D = 2.00685;
constexpr float  M0B = (float)dM0B, M0C = (float)dM0C, M0D = (float)dM0D;
constexpr float R0_m0 = 4.026f,  R0_g0 = 0.025f;   // BD chain, J=1
constexpr float R1_m0 = 2.4607f, R1_g0 = 0.0475f;  // BC chain, J=2
constexpr float R2_m0 = 2.4232f, R2_g0 = 0.025f;   // CD chain, J=1
constexpr float IQ0_0 = (float)(1.0 / cgetp(4.026,  dM0B, dM0D));
constexpr float IQ0_1 = (float)(1.0 / cgetp(2.4607, dM0B, dM0C));
constexpr float IQ0_2 = (float)(1.0 / cgetp(2.4232, dM0C, dM0D));

__device__ inline float getp(float M0, float M1, float M2){
  float s = M1 + M2, d = M1 - M2;
  float p = (M0 - s) * (M0 + s) * (M0 - d) * (M0 + d);
  float pp = 0.5f * (p + fabsf(p));
  return __builtin_amdgcn_sqrtf(pp) * (0.5f / M0);
}
__device__ inline cplx bw_eval(float m, float m0, float g0, float q, float iq0){
  float gamma = g0 * (q * iq0) * (m0 * __builtin_amdgcn_rcpf(m));
  float num    = m0 * gamma;
  float den_re = (m0 + m) * (m0 - m);
  float den_im = -m0 * gamma;
  float inv = __builtin_amdgcn_rcpf(fmaf(den_re, den_re, den_im * den_im));
  return { num * den_re * inv, -num * den_im * inv };
}
__device__ inline void halfang(float c, float& ch, float& sh){
  ch = __builtin_amdgcn_sqrtf((1.f + c) * 0.5f);
  sh = __builtin_amdgcn_sqrtf((1.f - c) * 0.5f);
}
__device__ inline cplx phase_neg(float phi){  // exp(-i*phi)
  return { __cosf(phi), -__sinf(phi) };
}

// ================= pre-kernel: uniform H couplings -> d_ws =================
__global__ void prep_htab_kernel(const float2* __restrict__ g_par, float2* __restrict__ ws){
  if (blockIdx.x != 0 || threadIdx.x != 0) return;
  cplx t[NH];
  compute_htab(g_par, t);
  #pragma unroll
  for (int k = 0; k < NH; ++k) ws[k] = make_float2(t[k].re, t[k].im);
}

// ================= main kernel =================
template<bool PRE>
__global__ void __launch_bounds__(256, 3)
AllAmplitude_59665685676511_kernel(
    const float* __restrict__ g_mBC,  const float* __restrict__ g_mBD,  const float* __restrict__ g_mCD,
    const float* __restrict__ g_cBC,  const float* __restrict__ g_cBBC, const float* __restrict__ g_pBC,  const float* __restrict__ g_pBBC,
    const float* __restrict__ g_cBD,  const float* __restrict__ g_cDBD, const float* __restrict__ g_pDBD,
    const float* __restrict__ g_cCD,  const float* __restrict__ g_cCCD, const float* __restrict__ g_pCD,  const float* __restrict__ g_pCCD,
    const float* __restrict__ g_cT1,  const float* __restrict__ g_cT2,  const float* __restrict__ g_p1,   const float* __restrict__ g_p2,
    const float2* __restrict__ g_par, const float2* __restrict__ hs,
    float* __restrict__ out, int n)
{
  int i = blockIdx.x * 256 + threadIdx.x;
  if (i >= n) return;

  cplx ht[NH];
  if constexpr (!PRE) compute_htab(g_par, ht);

  // ---------- res0 spine: G0[a][ (lD-lB)+1 ] ----------
  cplx G0[2][3];
  {
    float chBD, shBD, chDBD, shDBD;
    halfang(g_cBD[i],  chBD,  shBD);
    halfang(g_cDBD[i], chDBD, shDBD);
    float dBD[2][3], dDBD[3][3];
    static_for<0,2>([&](auto A_){ constexpr int a = decltype(A_)::value; constexpr int lA = 2*a-1;
      static_for<-1,2>([&](auto M_){ constexpr int m2 = decltype(M_)::value;
        dBD[a][m2+1] = wigner_d<1, lA, m2>(chBD, shBD); }); });
    static_for<-1,2>([&](auto M1_){ constexpr int m1 = decltype(M1_)::value;
      static_for<-1,2>([&](auto M2_){ constexpr int m2 = decltype(M2_)::value;
        dDBD[m1+1][m2+1] = wigner_d<1, m1, m2>(chDBD, shDBD); }); });
    static_for<0,2>([&](auto A_){ constexpr int a = decltype(A_)::value;
      static_for<0,3>([&](auto M_){ constexpr int mi = decltype(M_)::value;
        cplx acc{0.f, 0.f};
        static_for<-1,2>([&](auto L_){ constexpr int lDB = decltype(L_)::value;
          caxpy(acc, dBD[a][lDB+1] * dDBD[lDB+1][mi], GH(IH10(lDB)));
        });
        G0[a][mi] = acc; }); });
  }

  // ---------- res1 spine: V1[lB+1][lBC+2] ----------
  cplx V1[3][5];
  {
    float chT1, shT1, chBBC, shBBC;
    halfang(g_cT1[i],  chT1,  shT1);
    halfang(g_cBBC[i], chBBC, shBBC);
    cplx eP1 = phase_neg(g_p1[i] + g_pBBC[i]);
    cplx U1m = GH(IH21(-1)) * cconj(eP1);
    cplx U1p = GH(IH21( 1)) * eP1;
    float dT1[2][3], dBBC[5][2];
    static_for<0,2>([&](auto K_){ constexpr int k = decltype(K_)::value; constexpr int lB2 = 2*k-1;
      static_for<-1,2>([&](auto B_){ constexpr int lB = decltype(B_)::value;
        dT1[k][lB+1] = wigner_d<1, lB2, lB>(chT1, shT1); }); });
    static_for<-2,3>([&](auto C_){ constexpr int lBC = decltype(C_)::value;
      static_for<0,2>([&](auto K_){ constexpr int k = decltype(K_)::value; constexpr int lB2 = 2*k-1;
        dBBC[lBC+2][k] = wigner_d<2, lBC, lB2>(chBBC, shBBC); }); });
    static_for<-1,2>([&](auto B_){ constexpr int lB = decltype(B_)::value;
      static_for<-2,3>([&](auto C_){ constexpr int lBC = decltype(C_)::value;
        cplx acc{0.f, 0.f};
        caxpy(acc, dT1[0][lB+1] * dBBC[lBC+2][0], U1m);
        caxpy(acc, dT1[1][lB+1] * dBBC[lBC+2][1], U1p);
        V1[lB+1][lBC+2] = acc; }); });
  }

  // ---------- res2 spine: V2[lD+1][lCD+1] ----------
  cplx V2[3][3];
  {
    float chT2, shT2, chCCD, shCCD;
    halfang(g_cT2[i],  chT2,  shT2);
    halfang(g_cCCD[i], chCCD, shCCD);
    cplx eP2 = phase_neg(g_p2[i] + g_pCCD[i]);
    cplx U2[3];
    U2[0] = GH(IH22(-1)) * cconj(eP2);
    U2[1] = GH(IH22(0));
    U2[2] = GH(IH22(1)) * eP2;
    float dT2[3][3], dCCD[3][3];
    static_for<-1,2>([&](auto M1_){ constexpr int m1 = decltype(M1_)::value;
      static_for<-1,2>([&](auto M2_){ constexpr int m2 = decltype(M2_)::value;
        dT2[m1+1][m2+1]  = wigner_d<1, m1, m2>(chT2, shT2);
        dCCD[m1+1][m2+1] = wigner_d<1, m1, m2>(chCCD, shCCD); }); });
    static_for<-1,2>([&](auto D_){ constexpr int lD = decltype(D_)::value;
      static_for<-1,2>([&](auto C_){ constexpr int lCD = decltype(C_)::value;
        cplx acc{0.f, 0.f};
        static_for<-1,2>([&](auto X_){ constexpr int lC2 = decltype(X_)::value;
          caxpy(acc, dT2[lC2+1][lD+1] * dCCD[lCD+1][lC2+1], U2[lC2+1]);
        });
        V2[lD+1][lCD+1] = acc; }); });
  }

  // ---------- final-step d1 tables ----------
  float dBC[2][3], dCD[2][3];
  {
    float chBC, shBC, chCD, shCD;
    halfang(g_cBC[i], chBC, shBC);
    halfang(g_cCD[i], chCD, shCD);
    static_for<0,2>([&](auto A_){ constexpr int a = decltype(A_)::value; constexpr int lA = 2*a-1;
      static_for<-1,2>([&](auto M_){ constexpr int dm = decltype(M_)::value;
        dBC[a][dm+1] = wigner_d<1, lA, dm>(chBC, shBC);
        dCD[a][dm+1] = wigner_d<1, lA, dm>(chCD, shCD); }); });
  }

  // ---------- BW + phase folded coupling tables ----------
  const float mBC = g_mBC[i], mBD = g_mBD[i], mCD = g_mCD[i];
  const cplx bw0 = bw_eval(mBD, R0_m0, R0_g0, getp(mBD, M0B, M0D), IQ0_0);
  const cplx bw1 = bw_eval(mBC, R1_m0, R1_g0, getp(mBC, M0B, M0C), IQ0_1);
  const cplx bw2 = bw_eval(mCD, R2_m0, R2_g0, getp(mCD, M0C, M0D), IQ0_2);

  cplx W0T[3][3] = {};   // [lD+1][lB+1] : H2_0 * e_D^lD * bw0
  {
    const cplx eD = phase_neg(g_pDBD[i]);
    cplx EBW0[3] = { cconj(eD) * bw0, bw0, eD * bw0 };
    static_for<-1,2>([&](auto D_){ constexpr int lD = decltype(D_)::value;
      static_for<-1,2>([&](auto B_){ constexpr int lB = decltype(B_)::value;
        if constexpr (cabs_i(lD - lB) <= 1 && hnz<1,1,1,1,lD,lB>())
          W0T[lD+1][lB+1] = GH(IH20(lD,lB)) * EBW0[lD+1];
      }); });
  }
  cplx HT1[5][3] = {};   // [lBC+2][lD+1] : H1_1 * e_BC^lBC * bw1
  {
    const cplx eBC = phase_neg(g_pBC[i]);
    const cplx e2  = eBC * eBC;
    cplx T1B[5] = { cconj(e2) * bw1, cconj(eBC) * bw1, bw1, eBC * bw1, e2 * bw1 };
    static_for<-2,3>([&](auto C_){ constexpr int lBC = decltype(C_)::value;
      static_for<-1,2>([&](auto D_){ constexpr int lD = decltype(D_)::value;
        if constexpr (cabs_i(lBC - lD) <= 1 && hnz<2,1,2,1,lBC,lD>())
          HT1[lBC+2][lD+1] = GH(IH11(lBC,lD)) * T1B[lBC+2];
      }); });
  }
  cplx HT2[3][3] = {};   // [lCD+1][lB+1] : H1_2 * e_CD^lCD * bw2
  {
    const cplx eCD = phase_neg(g_pCD[i]);
    cplx T2B[3] = { cconj(eCD) * bw2, bw2, eCD * bw2 };
    static_for<-1,2>([&](auto C_){ constexpr int lCD = decltype(C_)::value;
      static_for<-1,2>([&](auto B_){ constexpr int lB = decltype(B_)::value;
        if constexpr (cabs_i(lCD - lB) <= 1 && hnz<4,1,1,1,lCD,lB>())
          HT2[lCD+1][lB+1] = GH(IH12(lCD,lB)) * T2B[lCD+1];
      }); });
  }

  // ---------- 18-combo helicity sum ----------
  float total = 0.f;
  static_for<-1,2>([&](auto B_){ constexpr int lB = decltype(B_)::value;
    static_for<-1,2>([&](auto D_){ constexpr int lD = decltype(D_)::value;
      // Y1[dm+1] = HT1(lD+dm, lD) * V1(lB, lD+dm)
      cplx Y1[3] = {};
      static_for<-1,2>([&](auto M_){ constexpr int dm = decltype(M_)::value; constexpr int lBC = lD + dm;
        if constexpr (hnz<2,1,2,1,lBC,lD>())
          Y1[dm+1] = HT1[lBC+2][lD+1] * V1[lB+1][lBC+2];
      });
      // Y2[dm+1] = HT2(lB+dm, lB) * V2(lD, lB+dm)
      cplx Y2[3] = {};
      static_for<-1,2>([&](auto M_){ constexpr int dm = decltype(M_)::value; constexpr int lCD = lB + dm;
        if constexpr (cabs_i(lCD) <= 1 && hnz<4,1,1,1,lCD,lB>())
          Y2[dm+1] = HT2[lCD+1][lB+1] * V2[lD+1][lCD+1];
      });
      static_for<0,2>([&](auto A_){ constexpr int a = decltype(A_)::value;
        cplx amp{0.f, 0.f};
        if constexpr (cabs_i(lD - lB) <= 1 && hnz<1,1,1,1,lD,lB>())
          amp = W0T[lD+1][lB+1] * G0[a][lD-lB+1];
        static_for<-1,2>([&](auto M_){ constexpr int dm = decltype(M_)::value; constexpr int lBC = lD + dm;
          if constexpr (hnz<2,1,2,1,lBC,lD>())
            caxpy(amp, dBC[a][dm+1], Y1[dm+1]);
        });
        static_for<-1,2>([&](auto M_){ constexpr int dm = decltype(M_)::value; constexpr int lCD = lB + dm;
          if constexpr (cabs_i(lCD) <= 1 && hnz<4,1,1,1,lCD,lB>())
            caxpy(amp, dCD[a][dm+1], Y2[dm+1]);
        });
        total = fmaf(amp.re, amp.re, total);
        total = fmaf(amp.im, amp.im, total);
      });
    });
  });

  out[i] = total;
}

// ================= launch =================
extern "C" void kernel_launch(void* const* d_in, const int* in_sizes, int n_in,
                              void* d_out, int out_size, void* d_ws, size_t ws_size,
                              hipStream_t stream) {
  (void)n_in; (void)out_size;
  const int n = in_sizes[0];
  const float*  mBC  = (const float*)d_in[0];
  const float*  mBD  = (const float*)d_in[1];
  const float*  mCD  = (const float*)d_in[2];
  const float*  cBC  = (const float*)d_in[3];
  const float*  cBBC = (const float*)d_in[4];
  const float*  pBC  = (const float*)d_in[5];
  const float*  pBBC = (const float*)d_in[6];
  const float*  cBD  = (const float*)d_in[7];
  const float*  cDBD = (const float*)d_in[8];
  const float*  pDBD = (const float*)d_in[9];
  const float*  cCD  = (const float*)d_in[10];
  const float*  cCCD = (const float*)d_in[11];
  const float*  pCD  = (const float*)d_in[12];
  const float*  pCCD = (const float*)d_in[13];
  const float*  cT1  = (const float*)d_in[14];
  const float*  cT2  = (const float*)d_in[15];
  const float*  p1   = (const float*)d_in[16];
  const float*  p2   = (const float*)d_in[17];
  const float2* parm = (const float2*)d_in[18];

  dim3 block(256);
  dim3 grid((n + 255) / 256);

  if (ws_size >= NH * sizeof(float2)) {
    prep_htab_kernel<<<1, 64, 0, stream>>>(parm, (float2*)d_ws);
    AllAmplitude_59665685676511_kernel<true><<<grid, block, 0, stream>>>(
        mBC, mBD, mCD, cBC, cBBC, pBC, pBBC, cBD, cDBD, pDBD,
        cCD, cCCD, pCD, pCCD, cT1, cT2, p1, p2, parm,
        (const float2*)d_ws, (float*)d_out, n);
  } else {
    AllAmplitude_59665685676511_kernel<false><<<grid, block, 0, stream>>>(
        mBC, mBD, mCD, cBC, cBBC, pBC, pBBC, cBD, cDBD, pDBD,
        cCD, cCCD, pCD, pCCD, cT1, cT2, p1, p2, parm,
        nullptr, (float*)d_out, n);
  }
}

// Round 3
// 54.284 us; speedup vs baseline: 5.0547x; 1.2066x over previous
//
#include <hip/hip_runtime.h>
#include <utility>
#include <type_traits>

typedef float f2 __attribute__((ext_vector_type(2)));

// ================= compile-time math (mirrors reference) =================
constexpr int cabs_i(int x){ return x < 0 ? -x : x; }
constexpr int cmax_i(int a, int b){ return a > b ? a : b; }
constexpr int cmin_i(int a, int b){ return a < b ? a : b; }
constexpr double cfact(int n){ double r = 1.0; for (int i = 2; i <= n; ++i) r *= (double)i; return r; }
constexpr double csqrt_d(double x){
  if (x <= 0.0) return 0.0;
  double r = x > 1.0 ? x : 1.0;
  for (int i = 0; i < 64; ++i) r = 0.5 * (r + x / r);
  return r;
}
constexpr double cg_coef(int j1,int j2,int m1,int m2,int j,int m){
  if (m1 + m2 != m || j < cabs_i(j1 - j2) || j > j1 + j2) return 0.0;
  if (cabs_i(m1) > j1 || cabs_i(m2) > j2 || cabs_i(m) > j) return 0.0;
  double pref = csqrt_d((2.0*j + 1.0) * cfact(j1+j2-j) * cfact(j+j1-j2) * cfact(j+j2-j1) / cfact(j1+j2+j+1));
  pref *= csqrt_d(cfact(j+m)*cfact(j-m)*cfact(j1-m1)*cfact(j1+m1)*cfact(j2-m2)*cfact(j2+m2));
  double s = 0.0;
  const int k0 = cmax_i(0, cmax_i(j2-j-m1, j1+m2-j));
  const int k1 = cmin_i(j1+j2-j, cmin_i(j1-m1, j2+m2));
  for (int k = k0; k <= k1; ++k){
    double t = 1.0/(cfact(k)*cfact(j1+j2-j-k)*cfact(j1-m1-k)*cfact(j2+m2-k)*cfact(j-j2+m1+k)*cfact(j-j1-m2+k));
    s += (k & 1) ? -t : t;
  }
  return pref * s;
}
constexpr double wd_coef(int j,int m1,int m2,int s){
  double pref = csqrt_d(cfact(j+m1)*cfact(j-m1)*cfact(j+m2)*cfact(j-m2));
  double c = pref / (cfact(j+m2-s)*cfact(s)*cfact(m1-m2+s)*cfact(j-m1-s));
  return ((m1-m2+s) & 1) ? -c : c;
}
constexpr double cgetp(double M0,double M1,double M2){
  double s = M1+M2, d = M1-M2;
  double p = (M0-s)*(M0+s)*(M0-d)*(M0+d);
  double pp = 0.5*(p + (p < 0 ? -p : p));
  return csqrt_d(pp)/(2.0*M0);
}

// ================= static_for =================
template<int Start, class F, int... Is>
__device__ inline void static_for_impl(F&& f, std::integer_sequence<int, Is...>){
  (f(std::integral_constant<int, Start + Is>{}), ...);
}
template<int Start, int End, class F>   // [Start, End)
__device__ inline void static_for(F&& f){
  if constexpr (End > Start)
    static_for_impl<Start>(static_cast<F&&>(f), std::make_integer_sequence<int, End - Start>{});
}

// ================= packed complex =================
__device__ inline f2 vfma2(f2 a, f2 b, f2 c){ return __builtin_elementwise_fma(a, b, c); }

struct cplx { f2 v; };   // v.x = re, v.y = im
__device__ inline cplx operator+(cplx a, cplx b){ return { a.v + b.v }; }
__device__ inline cplx operator*(cplx a, cplx b){
  f2 sw  = { -a.v.y, a.v.x };       // folds into pk neg modifier
  f2 bre = {  b.v.x, b.v.x };
  f2 bim = {  b.v.y, b.v.y };
  return { vfma2(a.v, bre, sw * bim) };   // 2 packed ops
}
__device__ inline cplx cconj(cplx a){ return { f2{ a.v.x, -a.v.y } }; }
__device__ inline void caxpy(cplx& acc, float r, cplx x){   // 1 packed fma
  f2 rr = { r, r };
  acc.v = vfma2(rr, x.v, acc.v);
}

template<int n> __device__ inline float ipow(float x){
  if constexpr (n <= 0) return 1.f;
  else return x * ipow<n-1>(x);
}
template<int n> __device__ inline f2 vpow(f2 x){
  if constexpr (n <= 0) return f2{1.f, 1.f};
  else return x * vpow<n-1>(x);
}

// ================= wigner d (coeffs folded at compile time) =================
template<int j, int m1, int m2>
__device__ inline float wigner_d(float ch, float sh){
  constexpr int s0 = cmax_i(0, m2 - m1);
  constexpr int s1 = cmin_i(j - m1, j + m2);
  float out = 0.f;
  static_for<s0, s1 + 1>([&](auto S){
    constexpr int s = decltype(S)::value;
    constexpr float coef = (float)wd_coef(j, m1, m2, s);
    out = fmaf(coef, ipow<2*j + m2 - m1 - 2*s>(ch) * ipow<m1 - m2 + 2*s>(sh), out);
  });
  return out;
}
// packed: two independent (ch,sh) pairs, same (j,m1,m2)
template<int j, int m1, int m2>
__device__ inline f2 wigner_d2(f2 ch, f2 sh){
  constexpr int s0 = cmax_i(0, m2 - m1);
  constexpr int s1 = cmin_i(j - m1, j + m2);
  f2 out = {0.f, 0.f};
  static_for<s0, s1 + 1>([&](auto S){
    constexpr int s = decltype(S)::value;
    constexpr float coef = (float)wd_coef(j, m1, m2, s);
    out = vfma2(f2{coef, coef}, vpow<2*j + m2 - m1 - 2*s>(ch) * vpow<m1 - m2 + 2*s>(sh), out);
  });
  return out;
}

// ================= static LS layout (from reference _build_layout) =================
struct LS { int l, s; };
template<int E> struct Entry;
template<> struct Entry<0>{ static constexpr int off = 0;  static constexpr int n = 2; static constexpr LS ls[2] = {{0,1},{2,1}}; };
template<> struct Entry<1>{ static constexpr int off = 2;  static constexpr int n = 3; static constexpr LS ls[3] = {{0,1},{2,1},{2,2}}; };
template<> struct Entry<2>{ static constexpr int off = 5;  static constexpr int n = 5; static constexpr LS ls[5] = {{0,1},{2,1},{2,2},{2,3},{4,3}}; };
template<> struct Entry<3>{ static constexpr int off = 10; static constexpr int n = 1; static constexpr LS ls[1] = {{2,1}}; };
template<> struct Entry<4>{ static constexpr int off = 11; static constexpr int n = 3; static constexpr LS ls[3] = {{0,1},{2,1},{2,2}}; };
template<> struct Entry<5>{ static constexpr int off = 14; static constexpr int n = 2; static constexpr LS ls[2] = {{0,1},{2,1}}; };

template<int E,int ja,int jb,int jc,int lb,int lc>
constexpr double hcoef(int idx){
  return cg_coef(jb, jc, lb, -lc, Entry<E>::ls[idx].s, lb - lc)
       * cg_coef(Entry<E>::ls[idx].l, Entry<E>::ls[idx].s, 0, lb - lc, ja, lb - lc);
}
template<int E,int ja,int jb,int jc,int lb,int lc>
constexpr bool hnz(){
  bool any = false;
  for (int i = 0; i < Entry<E>::n; ++i) if (hcoef<E,ja,jb,jc,lb,lc>(i) != 0.0) any = true;
  return any;
}
template<int E,int ja,int jb,int jc,int lb,int lc>
__device__ inline cplx H_ls(const cplx* par){
  cplx tot{ f2{0.f, 0.f} };
  static_for<0, Entry<E>::n>([&](auto I){
    constexpr double c = hcoef<E,ja,jb,jc,lb,lc>(decltype(I)::value);
    if constexpr (c != 0.0){
      caxpy(tot, (float)c, par[Entry<E>::off + decltype(I)::value]);
    }
  });
  return tot;
}

// ================= H table layout in d_ws =================
constexpr int IH10(int lDB){ return lDB+1; }                       // 0..2
constexpr int IH20(int lD,int lB){ return 3+(lD+1)*3+(lB+1); }     // 3..11
constexpr int IH11(int lBC,int lD){ return 12+(lBC+2)*3+(lD+1); }  // 12..26
constexpr int IH21(int lB2){ return 27+(lB2+1)/2; }                // 27..28
constexpr int IH12(int lCD,int lB){ return 29+(lCD+1)*3+(lB+1); }  // 29..37
constexpr int IH22(int lC2){ return 38+(lC2+1); }                  // 38..40
constexpr int NH = 41;

__device__ inline void compute_htab(const float2* __restrict__ g_par, cplx* t){
  cplx par[16];
  #pragma unroll
  for (int k = 0; k < 16; ++k){ float2 p = g_par[k]; par[k].v = f2{p.x, p.y}; }
  static_for<-1,2>([&](auto L){ constexpr int l = decltype(L)::value; t[IH10(l)] = H_ls<0,1,1,0,l,0>(par); });
  static_for<-1,2>([&](auto D){ constexpr int lD = decltype(D)::value;
    static_for<-1,2>([&](auto B){ constexpr int lB = decltype(B)::value;
      t[IH20(lD,lB)] = H_ls<1,1,1,1,lD,lB>(par); }); });
  static_for<-2,3>([&](auto C){ constexpr int lBC = decltype(C)::value;
    static_for<-1,2>([&](auto D){ constexpr int lD = decltype(D)::value;
      t[IH11(lBC,lD)] = H_ls<2,1,2,1,lBC,lD>(par); }); });
  t[IH21(-1)] = H_ls<3,2,1,0,-1,0>(par);
  t[IH21( 1)] = H_ls<3,2,1,0, 1,0>(par);
  static_for<-1,2>([&](auto C){ constexpr int lCD = decltype(C)::value;
    static_for<-1,2>([&](auto B){ constexpr int lB = decltype(B)::value;
      t[IH12(lCD,lB)] = H_ls<4,1,1,1,lCD,lB>(par); }); });
  static_for<-1,2>([&](auto C){ constexpr int lC2 = decltype(C)::value;
    t[IH22(lC2)] = H_ls<5,1,0,1,0,lC2>(par); });
}

template<int IDX, bool PRE>
__device__ inline cplx getH(const float2* __restrict__ hs, const cplx* ht){
  if constexpr (PRE){ float2 v = hs[IDX]; return cplx{ f2{v.x, v.y} }; }
  else return ht[IDX];
}
#define GH(IDX) getH<(IDX), PRE>(hs, ht)

// ================= physics constants =================
constexpr double dM0B = 2.01026, dM0C = 0.13957061, dM0D = 2.00685;
constexpr float  M0B = (float)dM0B, M0C = (float)dM0C, M0D = (float)dM0D;
constexpr float R0_m0 = 4.026f,  R0_g0 = 0.025f;   // BD chain, J=1
constexpr float R1_m0 = 2.4607f, R1_g0 = 0.0475f;  // BC chain, J=2
constexpr float R2_m0 = 2.4232f, R2_g0 = 0.025f;   // CD chain, J=1
constexpr float IQ0_0 = (float)(1.0 / cgetp(4.026,  dM0B, dM0D));
constexpr float IQ0_1 = (float)(1.0 / cgetp(2.4607, dM0B, dM0C));
constexpr float IQ0_2 = (float)(1.0 / cgetp(2.4232, dM0C, dM0D));

__device__ inline float getp(float M0, float M1, float M2){
  float s = M1 + M2, d = M1 - M2;
  float p = (M0 - s) * (M0 + s) * (M0 - d) * (M0 + d);
  float pp = 0.5f * (p + fabsf(p));
  return __builtin_amdgcn_sqrtf(pp) * (0.5f / M0);
}
__device__ inline cplx bw_eval(float m, float m0, float g0, float q, float iq0){
  float gamma = g0 * (q * iq0) * (m0 * __builtin_amdgcn_rcpf(m));
  float num    = m0 * gamma;
  float den_re = (m0 + m) * (m0 - m);
  float den_im = -m0 * gamma;
  float inv = __builtin_amdgcn_rcpf(fmaf(den_re, den_re, den_im * den_im));
  return { f2{ num * den_re * inv, -num * den_im * inv } };
}
__device__ inline void halfang(float c, float& ch, float& sh){
  ch = __builtin_amdgcn_sqrtf((1.f + c) * 0.5f);
  sh = __builtin_amdgcn_sqrtf((1.f - c) * 0.5f);
}
__device__ inline cplx phase_neg(float phi){  // exp(-i*phi)
  return { f2{ __cosf(phi), -__sinf(phi) } };
}

// ================= pre-kernel: uniform H couplings -> d_ws =================
__global__ void prep_htab_kernel(const float2* __restrict__ g_par, float2* __restrict__ ws){
  if (blockIdx.x != 0 || threadIdx.x != 0) return;
  cplx t[NH];
  compute_htab(g_par, t);
  #pragma unroll
  for (int k = 0; k < NH; ++k) ws[k] = make_float2(t[k].v.x, t[k].v.y);
}

// ================= main kernel =================
template<bool PRE>
__global__ void __launch_bounds__(256, 3)
AllAmplitude_59665685676511_kernel(
    const float* __restrict__ g_mBC,  const float* __restrict__ g_mBD,  const float* __restrict__ g_mCD,
    const float* __restrict__ g_cBC,  const float* __restrict__ g_cBBC, const float* __restrict__ g_pBC,  const float* __restrict__ g_pBBC,
    const float* __restrict__ g_cBD,  const float* __restrict__ g_cDBD, const float* __restrict__ g_pDBD,
    const float* __restrict__ g_cCD,  const float* __restrict__ g_cCCD, const float* __restrict__ g_pCD,  const float* __restrict__ g_pCCD,
    const float* __restrict__ g_cT1,  const float* __restrict__ g_cT2,  const float* __restrict__ g_p1,   const float* __restrict__ g_p2,
    const float2* __restrict__ g_par, const float2* __restrict__ hs,
    float* __restrict__ out, int n)
{
  int i = blockIdx.x * 256 + threadIdx.x;
  if (i >= n) return;

  cplx ht[NH];
  if constexpr (!PRE) compute_htab(g_par, ht);

  // ---------- all half-angles ----------
  float chBD, shBD, chDBD, shDBD, chBC, shBC, chBBC, shBBC;
  float chCD, shCD, chCCD, shCCD, chT1, shT1, chT2, shT2;
  halfang(g_cBD[i],  chBD,  shBD);
  halfang(g_cDBD[i], chDBD, shDBD);
  halfang(g_cBC[i],  chBC,  shBC);
  halfang(g_cBBC[i], chBBC, shBBC);
  halfang(g_cCD[i],  chCD,  shCD);
  halfang(g_cCCD[i], chCCD, shCCD);
  halfang(g_cT1[i],  chT1,  shT1);
  halfang(g_cT2[i],  chT2,  shT2);

  // ---------- packed wigner-d pair tables ----------
  // dBDT1[r][m+1]: .x = d^1_{2r-1,m}(BD), .y = d^1_{2r-1,m}(T1)
  f2 dBDT1[2][3];
  {
    f2 ch = { chBD, chT1 }, sh = { shBD, shT1 };
    static_for<0,2>([&](auto R_){ constexpr int r = decltype(R_)::value; constexpr int m1 = 2*r-1;
      static_for<-1,2>([&](auto M_){ constexpr int m2 = decltype(M_)::value;
        dBDT1[r][m2+1] = wigner_d2<1, m1, m2>(ch, sh); }); });
  }
  // dT2CCD[m1+1][m2+1]: .x = d^1_{m1,m2}(T2), .y = d^1_{m1,m2}(CCD)
  f2 dT2CCD[3][3];
  {
    f2 ch = { chT2, chCCD }, sh = { shT2, shCCD };
    static_for<-1,2>([&](auto M1_){ constexpr int m1 = decltype(M1_)::value;
      static_for<-1,2>([&](auto M2_){ constexpr int m2 = decltype(M2_)::value;
        dT2CCD[m1+1][m2+1] = wigner_d2<1, m1, m2>(ch, sh); }); });
  }
  // dBCCD[a][dm+1]: .x = d^1_{2a-1,dm}(BC), .y = d^1_{2a-1,dm}(CD)
  f2 dBCCD[2][3];
  {
    f2 ch = { chBC, chCD }, sh = { shBC, shCD };
    static_for<0,2>([&](auto A_){ constexpr int a = decltype(A_)::value; constexpr int lA = 2*a-1;
      static_for<-1,2>([&](auto M_){ constexpr int dm = decltype(M_)::value;
        dBCCD[a][dm+1] = wigner_d2<1, lA, dm>(ch, sh); }); });
  }
  // scalar tables
  float dDBD[3][3], dBBC[5][2];
  static_for<-1,2>([&](auto M1_){ constexpr int m1 = decltype(M1_)::value;
    static_for<-1,2>([&](auto M2_){ constexpr int m2 = decltype(M2_)::value;
      dDBD[m1+1][m2+1] = wigner_d<1, m1, m2>(chDBD, shDBD); }); });
  static_for<-2,3>([&](auto C_){ constexpr int lBC = decltype(C_)::value;
    static_for<0,2>([&](auto K_){ constexpr int k = decltype(K_)::value; constexpr int lB2 = 2*k-1;
      dBBC[lBC+2][k] = wigner_d<2, lBC, lB2>(chBBC, shBBC); }); });

  // ---------- res0 spine: G0[a][(lD-lB)+1] ----------
  cplx G0[2][3];
  static_for<0,2>([&](auto A_){ constexpr int a = decltype(A_)::value;
    static_for<0,3>([&](auto M_){ constexpr int mi = decltype(M_)::value;
      cplx acc{ f2{0.f, 0.f} };
      static_for<-1,2>([&](auto L_){ constexpr int lDB = decltype(L_)::value;
        caxpy(acc, dBDT1[a][lDB+1].x * dDBD[lDB+1][mi], GH(IH10(lDB)));
      });
      G0[a][mi] = acc; }); });

  // ---------- res1 spine: V1[lB+1][lBC+2] ----------
  cplx V1[3][5];
  {
    cplx eP1 = phase_neg(g_p1[i] + g_pBBC[i]);
    cplx U1m = GH(IH21(-1)) * cconj(eP1);
    cplx U1p = GH(IH21( 1)) * eP1;
    static_for<-1,2>([&](auto B_){ constexpr int lB = decltype(B_)::value;
      static_for<-2,3>([&](auto C_){ constexpr int lBC = decltype(C_)::value;
        cplx acc{ f2{0.f, 0.f} };
        caxpy(acc, dBDT1[0][lB+1].y * dBBC[lBC+2][0], U1m);
        caxpy(acc, dBDT1[1][lB+1].y * dBBC[lBC+2][1], U1p);
        V1[lB+1][lBC+2] = acc; }); });
  }

  // ---------- res2 spine: V2[lD+1][lCD+1] ----------
  cplx V2[3][3];
  {
    cplx eP2 = phase_neg(g_p2[i] + g_pCCD[i]);
    cplx U2[3];
    U2[0] = GH(IH22(-1)) * cconj(eP2);
    U2[1] = GH(IH22(0));
    U2[2] = GH(IH22(1)) * eP2;
    static_for<-1,2>([&](auto D_){ constexpr int lD = decltype(D_)::value;
      static_for<-1,2>([&](auto C_){ constexpr int lCD = decltype(C_)::value;
        cplx acc{ f2{0.f, 0.f} };
        static_for<-1,2>([&](auto X_){ constexpr int lC2 = decltype(X_)::value;
          caxpy(acc, dT2CCD[lC2+1][lD+1].x * dT2CCD[lCD+1][lC2+1].y, U2[lC2+1]);
        });
        V2[lD+1][lCD+1] = acc; }); });
  }

  // ---------- BW + phase folded coupling tables ----------
  const float mBC = g_mBC[i], mBD = g_mBD[i], mCD = g_mCD[i];
  const cplx bw0 = bw_eval(mBD, R0_m0, R0_g0, getp(mBD, M0B, M0D), IQ0_0);
  const cplx bw1 = bw_eval(mBC, R1_m0, R1_g0, getp(mBC, M0B, M0C), IQ0_1);
  const cplx bw2 = bw_eval(mCD, R2_m0, R2_g0, getp(mCD, M0C, M0D), IQ0_2);

  cplx W0T[3][3] = {};   // [lD+1][lB+1] : H2_0 * e_D^lD * bw0
  {
    const cplx eD = phase_neg(g_pDBD[i]);
    cplx EBW0[3] = { cconj(eD) * bw0, bw0, eD * bw0 };
    static_for<-1,2>([&](auto D_){ constexpr int lD = decltype(D_)::value;
      static_for<-1,2>([&](auto B_){ constexpr int lB = decltype(B_)::value;
        if constexpr (cabs_i(lD - lB) <= 1 && hnz<1,1,1,1,lD,lB>())
          W0T[lD+1][lB+1] = GH(IH20(lD,lB)) * EBW0[lD+1];
      }); });
  }
  cplx HT1[5][3] = {};   // [lBC+2][lD+1] : H1_1 * e_BC^lBC * bw1
  {
    const cplx eBC = phase_neg(g_pBC[i]);
    const cplx e2  = eBC * eBC;
    cplx T1B[5] = { cconj(e2) * bw1, cconj(eBC) * bw1, bw1, eBC * bw1, e2 * bw1 };
    static_for<-2,3>([&](auto C_){ constexpr int lBC = decltype(C_)::value;
      static_for<-1,2>([&](auto D_){ constexpr int lD = decltype(D_)::value;
        if constexpr (cabs_i(lBC - lD) <= 1 && hnz<2,1,2,1,lBC,lD>())
          HT1[lBC+2][lD+1] = GH(IH11(lBC,lD)) * T1B[lBC+2];
      }); });
  }
  cplx HT2[3][3] = {};   // [lCD+1][lB+1] : H1_2 * e_CD^lCD * bw2
  {
    const cplx eCD = phase_neg(g_pCD[i]);
    cplx T2B[3] = { cconj(eCD) * bw2, bw2, eCD * bw2 };
    static_for<-1,2>([&](auto C_){ constexpr int lCD = decltype(C_)::value;
      static_for<-1,2>([&](auto B_){ constexpr int lB = decltype(B_)::value;
        if constexpr (cabs_i(lCD - lB) <= 1 && hnz<4,1,1,1,lCD,lB>())
          HT2[lCD+1][lB+1] = GH(IH12(lCD,lB)) * T2B[lCD+1];
      }); });
  }

  // ---------- 18-combo helicity sum ----------
  float total = 0.f;
  static_for<-1,2>([&](auto B_){ constexpr int lB = decltype(B_)::value;
    static_for<-1,2>([&](auto D_){ constexpr int lD = decltype(D_)::value;
      // Y1[dm+1] = HT1(lD+dm, lD) * V1(lB, lD+dm)
      cplx Y1[3] = {};
      static_for<-1,2>([&](auto M_){ constexpr int dm = decltype(M_)::value; constexpr int lBC = lD + dm;
        if constexpr (hnz<2,1,2,1,lBC,lD>())
          Y1[dm+1] = HT1[lBC+2][lD+1] * V1[lB+1][lBC+2];
      });
      // Y2[dm+1] = HT2(lB+dm, lB) * V2(lD, lB+dm)
      cplx Y2[3] = {};
      static_for<-1,2>([&](auto M_){ constexpr int dm = decltype(M_)::value; constexpr int lCD = lB + dm;
        if constexpr (cabs_i(lCD) <= 1 && hnz<4,1,1,1,lCD,lB>())
          Y2[dm+1] = HT2[lCD+1][lB+1] * V2[lD+1][lCD+1];
      });
      static_for<0,2>([&](auto A_){ constexpr int a = decltype(A_)::value;
        cplx amp{ f2{0.f, 0.f} };
        if constexpr (cabs_i(lD - lB) <= 1 && hnz<1,1,1,1,lD,lB>())
          amp = W0T[lD+1][lB+1] * G0[a][lD-lB+1];
        static_for<-1,2>([&](auto M_){ constexpr int dm = decltype(M_)::value; constexpr int lBC = lD + dm;
          if constexpr (hnz<2,1,2,1,lBC,lD>())
            caxpy(amp, dBCCD[a][dm+1].x, Y1[dm+1]);
        });
        static_for<-1,2>([&](auto M_){ constexpr int dm = decltype(M_)::value; constexpr int lCD = lB + dm;
          if constexpr (cabs_i(lCD) <= 1 && hnz<4,1,1,1,lCD,lB>())
            caxpy(amp, dBCCD[a][dm+1].y, Y2[dm+1]);
        });
        total = fmaf(amp.v.x, amp.v.x, total);
        total = fmaf(amp.v.y, amp.v.y, total);
      });
    });
  });

  out[i] = total;
}

// ================= launch =================
extern "C" void kernel_launch(void* const* d_in, const int* in_sizes, int n_in,
                              void* d_out, int out_size, void* d_ws, size_t ws_size,
                              hipStream_t stream) {
  (void)n_in; (void)out_size;
  const int n = in_sizes[0];
  const float*  mBC  = (const float*)d_in[0];
  const float*  mBD  = (const float*)d_in[1];
  const float*  mCD  = (const float*)d_in[2];
  const float*  cBC  = (const float*)d_in[3];
  const float*  cBBC = (const float*)d_in[4];
  const float*  pBC  = (const float*)d_in[5];
  const float*  pBBC = (const float*)d_in[6];
  const float*  cBD  = (const float*)d_in[7];
  const float*  cDBD = (const float*)d_in[8];
  const float*  pDBD = (const float*)d_in[9];
  const float*  cCD  = (const float*)d_in[10];
  const float*  cCCD = (const float*)d_in[11];
  const float*  pCD  = (const float*)d_in[12];
  const float*  pCCD = (const float*)d_in[13];
  const float*  cT1  = (const float*)d_in[14];
  const float*  cT2  = (const float*)d_in[15];
  const float*  p1   = (const float*)d_in[16];
  const float*  p2   = (const float*)d_in[17];
  const float2* parm = (const float2*)d_in[18];

  dim3 block(256);
  dim3 grid((n + 255) / 256);

  if (ws_size >= NH * sizeof(float2)) {
    prep_htab_kernel<<<1, 64, 0, stream>>>(parm, (float2*)d_ws);
    AllAmplitude_59665685676511_kernel<true><<<grid, block, 0, stream>>>(
        mBC, mBD, mCD, cBC, cBBC, pBC, pBBC, cBD, cDBD, pDBD,
        cCD, cCCD, pCD, pCCD, cT1, cT2, p1, p2, parm,
        (const float2*)d_ws, (float*)d_out, n);
  } else {
    AllAmplitude_59665685676511_kernel<false><<<grid, block, 0, stream>>>(
        mBC, mBD, mCD, cBC, cBBC, pBC, pBBC, cBD, cDBD, pDBD,
        cCD, cCCD, pCD, pCCD, cT1, cT2, p1, p2, parm,
        nullptr, (float*)d_out, n);
  }
}